// Round 10
// baseline (1109.808 us; speedup 1.0000x reference)
//
#include <hip/hip_runtime.h>
#include <hip/hip_bf16.h>
#include <cstdint>

#define M_DIM 8192
#define K_DIM 4096
#define N_DIM 11008
#define NGROUPS 32

typedef __attribute__((ext_vector_type(4))) float f32x4;
typedef __attribute__((ext_vector_type(16))) float f32x16;
typedef __attribute__((ext_vector_type(8))) __bf16 bf16x8;

__device__ __forceinline__ unsigned int f2bf(float f) {
  unsigned int u = __builtin_bit_cast(unsigned int, f);
  return (u + 0x7FFFu + ((u >> 16) & 1u)) >> 16;   // RNE f32->bf16
}
__device__ __forceinline__ unsigned int pk2(float lo, float hi) {
  return f2bf(lo) | (f2bf(hi) << 16);
}

// ---- prepass A: fp32 -> bf16, 32x32x16-fragment-transposed ----
// granule layout: ws[rblk*131072 + kt*512 + lane*8 .. +8] =
//   A[rblk*32 + (lane&31)][kt*16 + (lane>>5)*8 .. +8]
// thread (rblk, kt, r): reads 16 f32 (64B contig), writes granules r and 32+r.
__global__ __launch_bounds__(256) void cvtA32_kernel(const float* __restrict__ in,
                                                     unsigned short* __restrict__ outA) {
  unsigned tid = blockIdx.x * 256 + threadIdx.x;
  unsigned r = tid & 31, kt = (tid >> 5) & 255, rblk = tid >> 13;
  const float* p = in + (size_t)(rblk * 32 + r) * K_DIM + kt * 16;
  float4 a0 = *(const float4*)p, a1 = *(const float4*)(p + 4);
  float4 b0 = *(const float4*)(p + 8), b1 = *(const float4*)(p + 12);
  uint4 v0, v1;
  v0.x = pk2(a0.x, a0.y); v0.y = pk2(a0.z, a0.w);
  v0.z = pk2(a1.x, a1.y); v0.w = pk2(a1.z, a1.w);
  v1.x = pk2(b0.x, b0.y); v1.y = pk2(b0.z, b0.w);
  v1.z = pk2(b1.x, b1.y); v1.w = pk2(b1.z, b1.w);
  size_t gbase = (size_t)rblk * 131072 + (size_t)kt * 512;
  *(uint4*)(outA + gbase + r * 8) = v0;          // lane r   (k lo 8)
  *(uint4*)(outA + gbase + (32 + r) * 8) = v1;   // lane r+32 (k hi 8)
}

// ---- prepass W: int codes * scale -> bf16, fragment-transposed ----
__global__ __launch_bounds__(256) void deqW32_kernel(const int* __restrict__ wc,
                                                     const float* __restrict__ sc,
                                                     unsigned short* __restrict__ outB) {
  unsigned tid = blockIdx.x * 256 + threadIdx.x;
  unsigned c = tid & 31, kt = (tid >> 5) & 255, cblk = tid >> 13;
  unsigned col = cblk * 32 + c;
  float s = sc[col * NGROUPS + (kt >> 3)];       // k0 = kt*16, group = kt/8
  const int* p = wc + (size_t)col * K_DIM + kt * 16;
  int4 c0 = *(const int4*)p, c1 = *(const int4*)(p + 4);
  int4 c2 = *(const int4*)(p + 8), c3 = *(const int4*)(p + 12);
  uint4 v0, v1;
  v0.x = pk2((float)c0.x * s, (float)c0.y * s);
  v0.y = pk2((float)c0.z * s, (float)c0.w * s);
  v0.z = pk2((float)c1.x * s, (float)c1.y * s);
  v0.w = pk2((float)c1.z * s, (float)c1.w * s);
  v1.x = pk2((float)c2.x * s, (float)c2.y * s);
  v1.y = pk2((float)c2.z * s, (float)c2.w * s);
  v1.z = pk2((float)c3.x * s, (float)c3.y * s);
  v1.w = pk2((float)c3.z * s, (float)c3.w * s);
  size_t gbase = (size_t)cblk * 131072 + (size_t)kt * 512;
  *(uint4*)(outB + gbase + c * 8) = v0;
  *(uint4*)(outB + gbase + (32 + c) * 8) = v1;
}

// ====== barrier-free all-register GEMM: 4 independent 128x64 waves/block ======
#define TILES_N 86                 /* 11008 / 128 */
#define NB (32 * TILES_N)          /* (8192/256) x 86 = 2752, %8==0 */

__global__ __launch_bounds__(256, 2) void gemm10_kernel(
    const unsigned short* __restrict__ A,   // frag-transposed bf16
    const unsigned short* __restrict__ B,   // frag-transposed bf16
    const float* __restrict__ bias,
    float* __restrict__ out) {
  const int t = threadIdx.x;
  const int bid = blockIdx.x;
  const int wg = (bid & 7) * (NB / 8) + (bid >> 3);   // bijective XCD swizzle
  const int br = wg / TILES_N;
  const int bc = wg % TILES_N;
  const int m0 = br * 256;
  const int n0 = bc * 128;

  const int w = t >> 6;
  const int lane = t & 63;
  const int wm = w >> 1;   // 0..1 -> 128-row half
  const int wn = w & 1;    // 0..1 -> 64-col half

  // per-wave fragment base pointers (lane-adjusted)
  const unsigned short* aB[4];
#pragma unroll
  for (int i = 0; i < 4; ++i)
    aB[i] = A + (size_t)(br * 8 + wm * 4 + i) * 131072 + lane * 8;
  const unsigned short* bB[2];
#pragma unroll
  for (int j = 0; j < 2; ++j)
    bB[j] = B + (size_t)(bc * 4 + wn * 2 + j) * 131072 + lane * 8;

  f32x16 acc[4][2];   // 128 VGPR
#pragma unroll
  for (int i = 0; i < 4; ++i)
#pragma unroll
    for (int j = 0; j < 2; ++j)
      acc[i][j] = (f32x16)(0.f);

  bf16x8 Aa[4][2], Ba[2][2], Ab[4][2], Bb[2][2];

  // chunk c = K-elements [c*32, c*32+32) = frag-kt {2c, 2c+1}
#define LOADSET(SA, SB, c)                                                    \
  _Pragma("unroll") for (int i = 0; i < 4; ++i)                               \
  _Pragma("unroll") for (int k2 = 0; k2 < 2; ++k2)                            \
    SA[i][k2] = *(const bf16x8*)(aB[i] + (size_t)((c) * 2 + k2) * 512);       \
  _Pragma("unroll") for (int j = 0; j < 2; ++j)                               \
  _Pragma("unroll") for (int k2 = 0; k2 < 2; ++k2)                            \
    SB[j][k2] = *(const bf16x8*)(bB[j] + (size_t)((c) * 2 + k2) * 512);

#define MMASET(SA, SB)                                                        \
  __builtin_amdgcn_s_setprio(1);                                              \
  _Pragma("unroll") for (int k2 = 0; k2 < 2; ++k2)                            \
  _Pragma("unroll") for (int i = 0; i < 4; ++i)                               \
  _Pragma("unroll") for (int j = 0; j < 2; ++j)                               \
    acc[i][j] = __builtin_amdgcn_mfma_f32_32x32x16_bf16(SA[i][k2], SB[j][k2], \
                                                        acc[i][j], 0, 0, 0);  \
  __builtin_amdgcn_s_setprio(0);

  // prologue: chunk 0 -> set a
  LOADSET(Aa, Ba, 0)
  // main: 63 x 2 chunks; load next while computing current (compiler-scheduled)
  for (int it = 0; it < 63; ++it) {
    LOADSET(Ab, Bb, 2 * it + 1)
    MMASET(Aa, Ba)
    LOADSET(Aa, Ba, 2 * it + 2)
    MMASET(Ab, Bb)
  }
  LOADSET(Ab, Bb, 127)
  MMASET(Aa, Ba)
  MMASET(Ab, Bb)

  // epilogue: 32x32 C/D layout: col = lane&31, row = (r&3) + 8*(r>>2) + 4*(lane>>5)
#pragma unroll
  for (int j = 0; j < 2; ++j) {
    const int col = n0 + wn * 64 + j * 32 + (lane & 31);
    const float bv = bias[col];
#pragma unroll
    for (int i = 0; i < 4; ++i) {
      const int rowb = m0 + wm * 128 + i * 32 + ((lane >> 5) << 2);
#pragma unroll
      for (int r = 0; r < 16; ++r) {
        const int row = rowb + (r & 3) + 8 * (r >> 2);
        out[(size_t)row * N_DIM + col] = acc[i][j][r] + bv;
      }
    }
  }
#undef LOADSET
#undef MMASET
}

// ================= fallback: 128x128 inline-dequant GEMM =================
#define FBM 128
#define FBN 128
#define FBK 64
#define FNT_N 86
#define FNT_M 64
#define FNB (FNT_N * FNT_M)

__global__ __launch_bounds__(256, 2) void gemm_fb_kernel(
    const float* __restrict__ Ain, const int* __restrict__ Wcodes,
    const float* __restrict__ scales, const float* __restrict__ bias,
    float* __restrict__ out) {
  __shared__ unsigned short lsA[FBM * FBK];
  __shared__ unsigned short lsB[FBN * FBK];

  const int t = threadIdx.x;
  const int bid = blockIdx.x;
  const int wg = (bid & 7) * (FNB / 8) + (bid >> 3);
  const int m0 = (wg / FNT_N) * FBM;
  const int n0 = (wg % FNT_N) * FBN;

  const int w = t >> 6;
  const int lane = t & 63;
  const int wm = w >> 1, wn = w & 1;
  const int srow = t >> 3;
  const int sp = t & 7;
  const int skc = sp ^ (srow & 7);

  f32x4 acc[4][4];
#pragma unroll
  for (int i = 0; i < 4; ++i)
#pragma unroll
    for (int j = 0; j < 4; ++j) {
      f32x4 z = {0.f, 0.f, 0.f, 0.f};
      acc[i][j] = z;
    }

  for (int kt = 0; kt < K_DIM / FBK; ++kt) {
    const int kg = kt * FBK + skc * 8;
#pragma unroll
    for (int c = 0; c < 4; ++c) {
      const int arow = m0 + c * 32 + srow;
      const float* ap = Ain + (size_t)arow * K_DIM + kg;
      float4 a0 = *(const float4*)ap;
      float4 a1 = *(const float4*)(ap + 4);
      uint4 va;
      va.x = pk2(a0.x, a0.y); va.y = pk2(a0.z, a0.w);
      va.z = pk2(a1.x, a1.y); va.w = pk2(a1.z, a1.w);
      *(uint4*)&lsA[(c * 32 + srow) * FBK + sp * 8] = va;

      const int nrow = n0 + c * 32 + srow;
      const float s = scales[nrow * NGROUPS + (kg >> 7)];
      const int4* wp = (const int4*)(Wcodes + (size_t)nrow * K_DIM + kg);
      int4 c0 = wp[0], c1 = wp[1];
      uint4 vb;
      vb.x = pk2((float)c0.x * s, (float)c0.y * s);
      vb.y = pk2((float)c0.z * s, (float)c0.w * s);
      vb.z = pk2((float)c1.x * s, (float)c1.y * s);
      vb.w = pk2((float)c1.z * s, (float)c1.w * s);
      *(uint4*)&lsB[(c * 32 + srow) * FBK + sp * 8] = vb;
    }
    __syncthreads();
#pragma unroll
    for (int kk = 0; kk < 2; ++kk) {
      bf16x8 af[4], bfr[4];
#pragma unroll
      for (int i = 0; i < 4; ++i) {
        const int row = wm * 64 + i * 16 + (lane & 15);
        const int pg = (kk * 4 + (lane >> 4)) ^ (row & 7);
        af[i] = *(const bf16x8*)&lsA[row * FBK + pg * 8];
      }
#pragma unroll
      for (int j = 0; j < 4; ++j) {
        const int row = wn * 64 + j * 16 + (lane & 15);
        const int pg = (kk * 4 + (lane >> 4)) ^ (row & 7);
        bfr[j] = *(const bf16x8*)&lsB[row * FBK + pg * 8];
      }
#pragma unroll
      for (int i = 0; i < 4; ++i)
#pragma unroll
        for (int j = 0; j < 4; ++j)
          acc[i][j] = __builtin_amdgcn_mfma_f32_16x16x32_bf16(af[i], bfr[j], acc[i][j], 0, 0, 0);
    }
    __syncthreads();
  }

  const int colb = n0 + wn * 64 + (lane & 15);
  const int rowb = m0 + wm * 64 + ((lane >> 4) << 2);
#pragma unroll
  for (int j = 0; j < 4; ++j) {
    const int col = colb + j * 16;
    const float bv = bias[col];
#pragma unroll
    for (int i = 0; i < 4; ++i) {
      const int row = rowb + i * 16;
#pragma unroll
      for (int r = 0; r < 4; ++r)
        out[(size_t)(row + r) * N_DIM + col] = acc[i][j][r] + bv;
    }
  }
}

extern "C" void kernel_launch(void* const* d_in, const int* in_sizes, int n_in,
                              void* d_out, int out_size, void* d_ws, size_t ws_size,
                              hipStream_t stream) {
  const float* Ain = (const float*)d_in[0];
  const int* Wc = (const int*)d_in[1];
  const float* sc = (const float*)d_in[2];
  const float* bias = (const float*)d_in[3];
  float* out = (float*)d_out;

  const size_t needA = (size_t)M_DIM * K_DIM * 2;
  const size_t needB = (size_t)N_DIM * K_DIM * 2;
  if (ws_size >= needA + needB) {
    unsigned short* wsA = (unsigned short*)d_ws;
    unsigned short* wsB = (unsigned short*)((char*)d_ws + needA);
    cvtA32_kernel<<<(unsigned)((size_t)M_DIM * K_DIM / 16 / 256), 256, 0, stream>>>(Ain, wsA);
    deqW32_kernel<<<(unsigned)((size_t)N_DIM * K_DIM / 16 / 256), 256, 0, stream>>>(Wc, sc, wsB);
    gemm10_kernel<<<NB, 256, 0, stream>>>(wsA, wsB, bias, out);
  } else {
    gemm_fb_kernel<<<FNB, 256, 0, stream>>>(Ain, Wc, sc, bias, out);
  }
}

// Round 11
// 522.495 us; speedup vs baseline: 2.1241x; 2.1241x over previous
//
#include <hip/hip_runtime.h>
#include <hip/hip_bf16.h>
#include <cstdint>

#define M_DIM 8192
#define K_DIM 4096
#define N_DIM 11008
#define NGROUPS 32

typedef __attribute__((ext_vector_type(4))) float f32x4;
typedef __attribute__((ext_vector_type(4))) int i32x4;
typedef __attribute__((ext_vector_type(8))) __bf16 bf16x8;

__device__ __forceinline__ unsigned int f2bf(float f) {
  unsigned int u = __builtin_bit_cast(unsigned int, f);
  return (u + 0x7FFFu + ((u >> 16) & 1u)) >> 16;
}
__device__ __forceinline__ unsigned int pk2(float lo, float hi) {
  return f2bf(lo) | (f2bf(hi) << 16);
}

// ---- prepass A: per-row int8 quantization (1 wave per row) ----
__global__ __launch_bounds__(256) void quantA_kernel(const float* __restrict__ in,
                                                     char* __restrict__ outA,
                                                     float* __restrict__ sA) {
  const int row = blockIdx.x * 4 + (threadIdx.x >> 6);
  const int lane = threadIdx.x & 63;
  const float* p = in + (size_t)row * K_DIM;
  float mx = 0.f;
#pragma unroll
  for (int e = 0; e < 16; ++e) {
    float4 v = *(const float4*)(p + e * 256 + lane * 4);
    mx = fmaxf(mx, fmaxf(fmaxf(fabsf(v.x), fabsf(v.y)), fmaxf(fabsf(v.z), fabsf(v.w))));
  }
#pragma unroll
  for (int off = 32; off; off >>= 1) mx = fmaxf(mx, __shfl_xor(mx, off));
  mx = fmaxf(mx, 1e-30f);
  const float rq = 127.f / mx;
  if (lane == 0) sA[row] = mx / 127.f;
  char* op = outA + (size_t)row * K_DIM;
#pragma unroll
  for (int e = 0; e < 16; ++e) {
    float4 v = *(const float4*)(p + e * 256 + lane * 4);
    unsigned pk = ((unsigned)((int)rintf(v.x * rq)) & 0xFFu)
                | (((unsigned)((int)rintf(v.y * rq)) & 0xFFu) << 8)
                | (((unsigned)((int)rintf(v.z * rq)) & 0xFFu) << 16)
                | (((unsigned)((int)rintf(v.w * rq)) & 0xFFu) << 24);
    *(unsigned*)(op + e * 256 + lane * 4) = pk;
  }
}

// ---- prepass W: per-column int8 re-quantization (1 wave per column) ----
// codes are int4-exact; only error is re-rounding onto the per-column grid.
__global__ __launch_bounds__(256) void quantW_kernel(const int* __restrict__ wc,
                                                     const float* __restrict__ sc,
                                                     char* __restrict__ outB,
                                                     float* __restrict__ sW) {
  const int col = blockIdx.x * 4 + (threadIdx.x >> 6);
  const int lane = threadIdx.x & 63;
  const int4* p = (const int4*)(wc + (size_t)col * K_DIM);
  const float* scp = sc + col * NGROUPS;
  float mx = 0.f;
#pragma unroll
  for (int e = 0; e < 16; ++e) {
    int4 c = p[e * 64 + lane];
    float s = scp[e * 2 + (lane >> 5)];
    float m = fmaxf(fmaxf(fabsf((float)c.x), fabsf((float)c.y)),
                    fmaxf(fabsf((float)c.z), fabsf((float)c.w)));
    mx = fmaxf(mx, m * s);
  }
#pragma unroll
  for (int off = 32; off; off >>= 1) mx = fmaxf(mx, __shfl_xor(mx, off));
  mx = fmaxf(mx, 1e-30f);
  const float rq = 127.f / mx;
  if (lane == 0) sW[col] = mx / 127.f;
  char* op = outB + (size_t)col * K_DIM;
#pragma unroll
  for (int e = 0; e < 16; ++e) {
    int4 c = p[e * 64 + lane];
    float s = scp[e * 2 + (lane >> 5)] * rq;
    unsigned pk = ((unsigned)((int)rintf((float)c.x * s)) & 0xFFu)
                | (((unsigned)((int)rintf((float)c.y * s)) & 0xFFu) << 8)
                | (((unsigned)((int)rintf((float)c.z * s)) & 0xFFu) << 16)
                | (((unsigned)((int)rintf((float)c.w * s)) & 0xFFu) << 24);
    *(unsigned*)(op + e * 256 + lane * 4) = pk;
  }
}

__device__ __forceinline__ void gload16(const void* g, void* l) {
  __builtin_amdgcn_global_load_lds((const __attribute__((address_space(1))) void*)g,
                                   (__attribute__((address_space(3))) void*)l,
                                   16, 0, 0);
}

// ====== i8 GEMM: R2-proven 256x256 structure, BK=64 i8 (same 64 B/row math) ======
#define BM 256
#define BN 256
#define BKB 64                     /* bytes = i8 elems per K-tile */
#define NKT (K_DIM / BKB)          /* 64 */
#define TILES_M (M_DIM / BM)       /* 32 */
#define TILES_N (N_DIM / BN)       /* 43 */
#define NB2 (TILES_M * TILES_N)    /* 1376, %8==0 */
#define TSZ (BM * BKB)             /* 16384 B per buffer */

#define VMCNT_(n) asm volatile("s_waitcnt vmcnt(" #n ")" ::: "memory")
#define VMCNT(n) VMCNT_(n)
#define BAR() __builtin_amdgcn_s_barrier()

__global__ __launch_bounds__(512, 2) void gemmq_kernel(
    const char* __restrict__ A,    // i8 [M][K]
    const char* __restrict__ B,    // i8 [N][K]
    const float* __restrict__ sA,  // per-row A scale
    const float* __restrict__ sW,  // per-col W scale
    const float* __restrict__ bias,
    float* __restrict__ out) {
  __shared__ __align__(16) char lA[4][TSZ];   // 64 KiB
  __shared__ __align__(16) char lB[4][TSZ];   // 64 KiB

  const int t = threadIdx.x;
  const int bid = blockIdx.x;
  const int wg = (bid & 7) * (NB2 / 8) + (bid >> 3);   // bijective XCD swizzle
  const int m0 = (wg / TILES_N) * BM;
  const int n0 = (wg % TILES_N) * BN;

  const int w = t >> 6;
  const int lane = t & 63;
  const int wm = w >> 2;   // 0..1
  const int wn = w & 3;    // 0..3

  // staging (R2-verified byte math): rows are 64 B, 4 granules of 16 B.
  // thread: rows r0, r0+16; phys granule lane&3; source pre-swizzled ^(row>>1)&3.
  const int r0 = w * 32 + (lane >> 2);
  const int r1 = r0 + 16;
  const int pgs = lane & 3;
  const size_t aoff0 = (size_t)(m0 + r0) * K_DIM + (unsigned)(pgs ^ ((r0 >> 1) & 3)) * 16;
  const size_t aoff1 = (size_t)(m0 + r1) * K_DIM + (unsigned)(pgs ^ ((r1 >> 1) & 3)) * 16;
  const size_t boff0 = (size_t)(n0 + r0) * K_DIM + (unsigned)(pgs ^ ((r0 >> 1) & 3)) * 16;
  const size_t boff1 = (size_t)(n0 + r1) * K_DIM + (unsigned)(pgs ^ ((r1 >> 1) & 3)) * 16;
  const int ld0 = w * 2048;          // wave-uniform LDS byte base (rows w*32..+16)
  const int ld1 = w * 2048 + 1024;   // rows w*32+16..+16

  i32x4 acc[8][4];
#pragma unroll
  for (int i = 0; i < 8; ++i)
#pragma unroll
    for (int j = 0; j < 4; ++j) {
      i32x4 z = {0, 0, 0, 0};
      acc[i][j] = z;
    }

#define STAGE(buf, kt)                                                        \
  do {                                                                        \
    gload16(A + aoff0 + (size_t)(kt) * BKB, &lA[buf][ld0]);                   \
    gload16(A + aoff1 + (size_t)(kt) * BKB, &lA[buf][ld1]);                   \
    gload16(B + boff0 + (size_t)(kt) * BKB, &lB[buf][ld0]);                   \
    gload16(B + boff1 + (size_t)(kt) * BKB, &lB[buf][ld1]);                   \
  } while (0)

  // one phase per K-tile: read 12 frags, stage tile kt+3, 32 MFMA eq (16 i8), wait, bar
#define TILE_CORE(CB)                                                         \
  i32x4 af[8], bq[4];                                                         \
  _Pragma("unroll") for (int i = 0; i < 8; ++i) {                             \
    const int row = wm * 128 + i * 16 + (lane & 15);                          \
    const int pg = (lane >> 4) ^ ((row >> 1) & 3);                            \
    af[i] = *(const i32x4*)&lA[CB][row * 64 + pg * 16];                       \
  }                                                                           \
  _Pragma("unroll") for (int j = 0; j < 4; ++j) {                             \
    const int row = wn * 64 + j * 16 + (lane & 15);                           \
    const int pg = (lane >> 4) ^ ((row >> 1) & 3);                            \
    bq[j] = *(const i32x4*)&lB[CB][row * 64 + pg * 16];                       \
  }

#define TILE_MMA()                                                            \
  __builtin_amdgcn_s_setprio(1);                                              \
  _Pragma("unroll") for (int i = 0; i < 8; ++i)                               \
  _Pragma("unroll") for (int j = 0; j < 4; ++j)                               \
    acc[i][j] = __builtin_amdgcn_mfma_i32_16x16x64_i8(af[i], bq[j],           \
                                                      acc[i][j], 0, 0, 0);    \
  __builtin_amdgcn_s_setprio(0);

#define TILE(CB, SB, KT3, VN)                                                 \
  {                                                                           \
    TILE_CORE(CB)                                                             \
    STAGE(SB, KT3);                                                           \
    TILE_MMA()                                                                \
    VMCNT(VN);                                                                \
    BAR();                                                                    \
  }
#define TILE_NS(CB, VN)                                                       \
  {                                                                           \
    TILE_CORE(CB)                                                             \
    TILE_MMA()                                                                \
    VMCNT(VN);                                                                \
    BAR();                                                                    \
  }

  // prologue: stage tiles 0,1,2 (12 loads); retire tile 0 (leave 8 in flight)
  STAGE(0, 0);
  STAGE(1, 1);
  STAGE(2, 2);
  VMCNT(8);
  BAR();

  // main: tiles 0..59, staging 3..62; VMCNT(8) retires exactly tile kt+1
  for (int it = 0; it < 15; ++it) {
    const int k = it * 4;
    TILE(0, 3, k + 3, 8)
    TILE(1, 0, k + 4, 8)
    TILE(2, 1, k + 5, 8)
    TILE(3, 2, k + 6, 8)
  }
  // tile 60: stage 63; then drain 8 -> 4 -> 0
  TILE(0, 3, 63, 8)
  TILE_NS(1, 4)
  TILE_NS(2, 0)
  {  // tile 63: nothing outstanding
    TILE_CORE(3)
    TILE_MMA()
  }

  // epilogue: C col = lane&15, row = (lane>>4)*4 + r (dtype-independent layout)
  const int colb = n0 + wn * 64 + (lane & 15);
  const int rowb = m0 + wm * 128 + ((lane >> 4) << 2);
  float sar[8][4];
#pragma unroll
  for (int ai = 0; ai < 8; ++ai)
#pragma unroll
    for (int r = 0; r < 4; ++r)
      sar[ai][r] = sA[rowb + ai * 16 + r];
#pragma unroll
  for (int j = 0; j < 4; ++j) {
    const int col = colb + j * 16;
    const float sc2 = sW[col];
    const float bv = bias[col];
#pragma unroll
    for (int ai = 0; ai < 8; ++ai) {
      const int row = rowb + ai * 16;
#pragma unroll
      for (int r = 0; r < 4; ++r)
        out[(size_t)(row + r) * N_DIM + col] =
            (float)acc[ai][j][r] * sar[ai][r] * sc2 + bv;
    }
  }
#undef STAGE
#undef TILE_CORE
#undef TILE_MMA
#undef TILE
#undef TILE_NS
}

// ================= fallback: 128x128 inline-dequant GEMM =================
#define FBM 128
#define FBN 128
#define FBK 64
#define FNT_N 86
#define FNT_M 64
#define FNB (FNT_N * FNT_M)

__global__ __launch_bounds__(256, 2) void gemm_fb_kernel(
    const float* __restrict__ Ain, const int* __restrict__ Wcodes,
    const float* __restrict__ scales, const float* __restrict__ bias,
    float* __restrict__ out) {
  __shared__ unsigned short lsA[FBM * FBK];
  __shared__ unsigned short lsB[FBN * FBK];

  const int t = threadIdx.x;
  const int bid = blockIdx.x;
  const int wg = (bid & 7) * (FNB / 8) + (bid >> 3);
  const int m0 = (wg / FNT_N) * FBM;
  const int n0 = (wg % FNT_N) * FBN;

  const int w = t >> 6;
  const int lane = t & 63;
  const int wm = w >> 1, wn = w & 1;
  const int srow = t >> 3;
  const int sp = t & 7;
  const int skc = sp ^ (srow & 7);

  f32x4 acc[4][4];
#pragma unroll
  for (int i = 0; i < 4; ++i)
#pragma unroll
    for (int j = 0; j < 4; ++j) {
      f32x4 z = {0.f, 0.f, 0.f, 0.f};
      acc[i][j] = z;
    }

  for (int kt = 0; kt < K_DIM / FBK; ++kt) {
    const int kg = kt * FBK + skc * 8;
#pragma unroll
    for (int c = 0; c < 4; ++c) {
      const int arow = m0 + c * 32 + srow;
      const float* ap = Ain + (size_t)arow * K_DIM + kg;
      float4 a0 = *(const float4*)ap;
      float4 a1 = *(const float4*)(ap + 4);
      uint4 va;
      va.x = pk2(a0.x, a0.y); va.y = pk2(a0.z, a0.w);
      va.z = pk2(a1.x, a1.y); va.w = pk2(a1.z, a1.w);
      *(uint4*)&lsA[(c * 32 + srow) * FBK + sp * 8] = va;

      const int nrow = n0 + c * 32 + srow;
      const float s = scales[nrow * NGROUPS + (kg >> 7)];
      const int4* wp = (const int4*)(Wcodes + (size_t)nrow * K_DIM + kg);
      int4 c0 = wp[0], c1 = wp[1];
      uint4 vb;
      vb.x = pk2((float)c0.x * s, (float)c0.y * s);
      vb.y = pk2((float)c0.z * s, (float)c0.w * s);
      vb.z = pk2((float)c1.x * s, (float)c1.y * s);
      vb.w = pk2((float)c1.z * s, (float)c1.w * s);
      *(uint4*)&lsB[(c * 32 + srow) * FBK + sp * 8] = vb;
    }
    __syncthreads();
#pragma unroll
    for (int kk = 0; kk < 2; ++kk) {
      bf16x8 af[4], bfr[4];
#pragma unroll
      for (int i = 0; i < 4; ++i) {
        const int row = wm * 64 + i * 16 + (lane & 15);
        const int pg = (kk * 4 + (lane >> 4)) ^ (row & 7);
        af[i] = *(const bf16x8*)&lsA[row * FBK + pg * 8];
      }
#pragma unroll
      for (int j = 0; j < 4; ++j) {
        const int row = wn * 64 + j * 16 + (lane & 15);
        const int pg = (kk * 4 + (lane >> 4)) ^ (row & 7);
        bfr[j] = *(const bf16x8*)&lsB[row * FBK + pg * 8];
      }
#pragma unroll
      for (int i = 0; i < 4; ++i)
#pragma unroll
        for (int j = 0; j < 4; ++j)
          acc[i][j] = __builtin_amdgcn_mfma_f32_16x16x32_bf16(af[i], bfr[j], acc[i][j], 0, 0, 0);
    }
    __syncthreads();
  }

  const int colb = n0 + wn * 64 + (lane & 15);
  const int rowb = m0 + wm * 64 + ((lane >> 4) << 2);
#pragma unroll
  for (int j = 0; j < 4; ++j) {
    const int col = colb + j * 16;
    const float bv = bias[col];
#pragma unroll
    for (int i = 0; i < 4; ++i) {
      const int row = rowb + i * 16;
#pragma unroll
      for (int r = 0; r < 4; ++r)
        out[(size_t)(row + r) * N_DIM + col] = acc[i][j][r] + bv;
    }
  }
}

extern "C" void kernel_launch(void* const* d_in, const int* in_sizes, int n_in,
                              void* d_out, int out_size, void* d_ws, size_t ws_size,
                              hipStream_t stream) {
  const float* Ain = (const float*)d_in[0];
  const int* Wc = (const int*)d_in[1];
  const float* sc = (const float*)d_in[2];
  const float* bias = (const float*)d_in[3];
  float* out = (float*)d_out;

  const size_t offW = (size_t)M_DIM * K_DIM;            // A_i8: 32 MiB
  const size_t offSA = offW + (size_t)N_DIM * K_DIM;    // W_i8: 43 MiB
  const size_t offSW = offSA + (size_t)M_DIM * 4;       // sA: 32 KiB
  const size_t need = offSW + (size_t)N_DIM * 4;        // sW: 43 KiB

  if (ws_size >= need) {
    char* wsA = (char*)d_ws;
    char* wsB = (char*)d_ws + offW;
    float* sA = (float*)((char*)d_ws + offSA);
    float* sW = (float*)((char*)d_ws + offSW);
    quantA_kernel<<<M_DIM / 4, 256, 0, stream>>>(Ain, wsA, sA);
    quantW_kernel<<<N_DIM / 4, 256, 0, stream>>>(Wc, sc, wsB, sW);
    gemmq_kernel<<<NB2, 512, 0, stream>>>(wsA, wsB, sA, sW, bias, out);
  } else {
    gemm_fb_kernel<<<FNB, 256, 0, stream>>>(Ain, Wc, sc, bias, out);
  }
}